// Round 1
// 792.913 us; speedup vs baseline: 1.0935x; 1.0935x over previous
//
#include <hip/hip_runtime.h>
#include <math.h>

#define B 4
#define T 512
#define I 512
#define H 8
#define D 512
#define V 32000
#define HASH_SZ 1024          // >= 2x max unique tokens per batch (512) -> load factor <= 0.5
#define BM_WORDS (V / 32)     // 1000 words = 4000 B bitmap of hit vocab slots

// ---------------- K1: attn = mean over heads, (B,H,T,I) -> (B,T,I) ----------
__global__ void k_attn_mean(const float* __restrict__ ah, float* __restrict__ attn) {
    long long idx4 = (long long)blockIdx.x * blockDim.x + threadIdx.x; // float4 index
    const long long total4 = (long long)B * T * I / 4;
    if (idx4 >= total4) return;
    long long flat = idx4 * 4;
    long long b = flat / ((long long)T * I);
    long long rem = flat - b * (long long)T * I;
    const float4* src = (const float4*)(ah + b * (long long)H * T * I + rem);
    const long long stride4 = (long long)T * I / 4;
    float4 s = src[0];
#pragma unroll
    for (int h = 1; h < H; ++h) {
        float4 x = src[h * stride4];
        s.x += x.x; s.y += x.y; s.z += x.z; s.w += x.w;
    }
    const float r = 1.0f / (float)H;
    s.x *= r; s.y *= r; s.z *= r; s.w *= r;
    ((float4*)attn)[idx4] = s;
}

// ---------------- K2a: per-batch token dedup: leader[i] = min j, tok[j]==tok[i]
__global__ void k_leaders(const int* __restrict__ tok, int* __restrict__ leader) {
    __shared__ int t_lds[I];
    const int b = blockIdx.x;
    const int i = threadIdx.x;             // blockDim.x == I == 512
    t_lds[i] = tok[b * I + i];
    __syncthreads();
    const int mytok = t_lds[i];
    int lead = i;
    for (int j = 0; j < i; ++j) {
        if (t_lds[j] == mytok) { lead = j; break; }
    }
    leader[b * I + i] = lead;
}

// ---------------- K2b: vb[b,i] = enc[b,i,:] . W[0:D]  (one wave per row) ----
__global__ void k_vb(const float* __restrict__ enc, const float* __restrict__ W,
                     float* __restrict__ vb) {
    const int row = blockIdx.x * 4 + (threadIdx.x >> 6);   // b*I + i
    const int lane = threadIdx.x & 63;
    const float* e = enc + (long long)row * D;
    float p = 0.f;
    for (int d = lane; d < D; d += 64) p += e[d] * W[d];
#pragma unroll
    for (int o = 32; o > 0; o >>= 1) p += __shfl_down(p, o, 64);
    if (lane == 0) vb[row] = p;
}

// ---------------- K2c: p_gen[b,t] = sigmoid(attn.vb + dec.Wd + tar.Wt + b0) -
__global__ void k_pgen(const float* __restrict__ attn, const float* __restrict__ vb,
                       const float* __restrict__ dec, const float* __restrict__ tar,
                       const float* __restrict__ W, const float* __restrict__ bptr,
                       float* __restrict__ pgen) {
    const int row = blockIdx.x * 4 + (threadIdx.x >> 6);   // b*T + t
    const int lane = threadIdx.x & 63;
    const int b = row / T;
    const float* ar = attn + (long long)row * I;
    const float* vr = vb + b * I;
    const float* dr = dec + (long long)row * D;
    const float* tr = tar + (long long)row * D;
    float p = 0.f;
    for (int k = lane; k < I; k += 64) p += ar[k] * vr[k];
    for (int k = lane; k < D; k += 64) p += dr[k] * W[D + k] + tr[k] * W[2 * D + k];
#pragma unroll
    for (int o = 32; o > 0; o >>= 1) p += __shfl_down(p, o, 64);
    if (lane == 0) {
        const float x = p + bptr[0];
        pgen[row] = 1.0f / (1.0f + __expf(-x));
    }
}

// ---------------- K3: per-(b,t) row — sparse softmax + gated mix ------------
// Single-pass version: per-row LDS bitmap of hit vocab slots + open-addressing
// LDS hash (slot -> exp(c)). The bulk float4 loop emits FINAL values directly;
// no scattered patch pass (which cost ~250 MB of extra HBM traffic: scattered
// gen re-reads + ECC RMW on partial-line 4B stores).
__device__ __forceinline__ float hash_probe(const int* hkey, const float* hval, int slot) {
    int h = slot & (HASH_SZ - 1);
    while (true) {                          // key guaranteed present (bitmap bit set)
        const int k = hkey[h];
        if (k == slot) return hval[h];
        h = (h + 1) & (HASH_SZ - 1);
    }
}

__global__ void __launch_bounds__(256) k_main(
    const float* __restrict__ attn, const int* __restrict__ tok,
    const int* __restrict__ leader, const float* __restrict__ gen,
    const float* __restrict__ pgen, float* __restrict__ final_out,
    float* __restrict__ pointer_out) {
    __shared__ float c[I];
    __shared__ int tk[I];
    __shared__ int ld[I];
    __shared__ unsigned bm[BM_WORDS];
    __shared__ int hkey[HASH_SZ];
    __shared__ float hval[HASH_SZ];
    __shared__ float red[4];
    __shared__ float s_inv, s_pg;
    // LDS total ~18.4 KB -> 8 blocks/CU still fits (146 KB < 160 KB); occupancy
    // remains wave-limited (4 waves/block * 8 = 32 waves/CU).

    const int row = blockIdx.x;            // b*T + t
    const int b = row / T;
    const int tid = threadIdx.x;

    const float* ar = attn + (long long)row * I;
    const int* tb = tok + b * I;
    const int* lb = leader + b * I;

    for (int i = tid; i < I; i += 256) { c[i] = 0.f; tk[i] = tb[i]; ld[i] = lb[i]; }
    for (int i = tid; i < BM_WORDS; i += 256) bm[i] = 0u;
    for (int i = tid; i < HASH_SZ; i += 256) hkey[i] = -1;
    __syncthreads();
    for (int i = tid; i < I; i += 256) atomicAdd(&c[ld[i]], ar[i]);
    __syncthreads();

    // Leaders: e = exp(c), insert into hash, set bitmap, accumulate denom.
    float local = 0.f;
    for (int i = tid; i < I; i += 256) {
        if (ld[i] == i) {                   // leader == unique vocab slot
            const int slot = tk[i];
            const float ei = __expf(c[i]);
            local += ei - 1.0f;             // denom = V + sum(exp(c)-1)
            atomicOr(&bm[slot >> 5], 1u << (slot & 31));
            int h = slot & (HASH_SZ - 1);
            while (atomicCAS(&hkey[h], -1, slot) != -1) h = (h + 1) & (HASH_SZ - 1);
            hval[h] = ei;                   // distinct slots per row -> no dup keys
        }
    }
#pragma unroll
    for (int o = 32; o > 0; o >>= 1) local += __shfl_down(local, o, 64);
    const int lane = tid & 63, w = tid >> 6;
    if (lane == 0) red[w] = local;
    __syncthreads();
    if (tid == 0) {
        const float denom = (float)V + red[0] + red[1] + red[2] + red[3];
        s_inv = 1.0f / denom;
        s_pg = pgen[row];
    }
    __syncthreads();

    const float inv = s_inv, pg = s_pg, omp = 1.0f - pg;
    const size_t base = (size_t)row * V;
    const float4* g4 = (const float4*)(gen + base);
    float4* f4 = (float4*)(final_out + base);
    float4* p4 = (float4*)(pointer_out + base);
    for (int v4 = tid; v4 < V / 4; v4 += 256) {
        const float4 g = g4[v4];
        // nibble of the hit-bitmap covering vocab slots [4*v4, 4*v4+3]
        const unsigned nib = (bm[v4 >> 3] >> ((v4 & 7) << 2)) & 0xFu;
        float4 p = make_float4(inv, inv, inv, inv);
        if (nib) {                          // ~6% of chunks per row
            const int s0 = v4 << 2;
            if (nib & 1u) p.x = hash_probe(hkey, hval, s0) * inv;
            if (nib & 2u) p.y = hash_probe(hkey, hval, s0 + 1) * inv;
            if (nib & 4u) p.z = hash_probe(hkey, hval, s0 + 2) * inv;
            if (nib & 8u) p.w = hash_probe(hkey, hval, s0 + 3) * inv;
        }
        float4 f;
        f.x = fmaf(pg, g.x, omp * p.x);
        f.y = fmaf(pg, g.y, omp * p.y);
        f.z = fmaf(pg, g.z, omp * p.z);
        f.w = fmaf(pg, g.w, omp * p.w);
        f4[v4] = f;
        p4[v4] = p;
    }
}

extern "C" void kernel_launch(void* const* d_in, const int* in_sizes, int n_in,
                              void* d_out, int out_size, void* d_ws, size_t ws_size,
                              hipStream_t stream) {
    const int* inp_tokens = (const int*)d_in[0];
    const float* tar = (const float*)d_in[1];
    const float* gen = (const float*)d_in[2];
    const float* enc = (const float*)d_in[3];
    const float* dec = (const float*)d_in[4];
    const float* ah  = (const float*)d_in[5];
    const float* W   = (const float*)d_in[6];
    const float* b0  = (const float*)d_in[7];

    float* out = (float*)d_out;
    const size_t BTV = (size_t)B * T * V;
    float* final_out   = out;
    float* pointer_out = out + BTV;
    float* pgen_out    = out + 2 * BTV;

    // workspace layout: attn (B*T*I f32) | leader (B*I i32) | vb (B*I f32)
    char* ws = (char*)d_ws;
    float* attn  = (float*)ws;
    int* leader  = (int*)(ws + sizeof(float) * (size_t)B * T * I);
    float* vb    = (float*)((char*)leader + sizeof(int) * (size_t)B * I);

    k_attn_mean<<<(B * T * I / 4 + 255) / 256, 256, 0, stream>>>(ah, attn);
    k_leaders<<<B, I, 0, stream>>>(inp_tokens, leader);
    k_vb<<<(B * I) / 4, 256, 0, stream>>>(enc, W, vb);
    k_pgen<<<(B * T) / 4, 256, 0, stream>>>(attn, vb, dec, tar, W, b0, pgen_out);
    k_main<<<B * T, 256, 0, stream>>>(attn, inp_tokens, leader, gen, pgen_out,
                                      final_out, pointer_out);
}